// Round 1
// baseline (373.369 us; speedup 1.0000x reference)
//
#include <hip/hip_runtime.h>

#define B 64
#define T 4096
#define U 256
#define SB 32            // pass1 blocks per batch
#define WPB 4            // waves per block
#define WBATCH (SB*WPB)  // 128 waves per batch

// ---------------- kernel 0: state[b,u] = decoder_s[b,:] @ Wa_w[:,u] + b[u] ----
__global__ __launch_bounds__(256) void state_kernel(
    const float* __restrict__ ds, const float* __restrict__ W,
    const float* __restrict__ bias, float* __restrict__ state)
{
    const int b = blockIdx.x, u = threadIdx.x;
    __shared__ float ss[U];
    ss[u] = ds[b * U + u];
    __syncthreads();
    float acc = bias[u];
#pragma unroll 8
    for (int d = 0; d < U; ++d) acc = fmaf(ss[d], W[d * U + u], acc);
    state[b * U + u] = acc;
}

// ---------------- kernel 1: fused score + online softmax + context partials ---
// Each wave handles strided t; lanes cover u (4 floats/lane). encoder_h read ONCE.
__global__ __launch_bounds__(256) void pass1(
    const float* __restrict__ h, const int* __restrict__ mask,
    const float* __restrict__ state, float* __restrict__ score,
    float* __restrict__ pm, float* __restrict__ pl, float* __restrict__ pacc)
{
    const int b    = blockIdx.x / SB;
    const int sblk = blockIdx.x % SB;
    const int tid  = threadIdx.x;
    const int wave = tid >> 6, lane = tid & 63;
    const int wi   = sblk * WPB + wave;          // wave index within batch, 0..127

    const float4 st = *(const float4*)(state + b * U + (lane << 2));
    const float* hb = h + (size_t)b * T * U;
    const int*   mb = mask + b * T;
    float*      scb = score + (size_t)b * T;

    float  m = -INFINITY, l = 0.f;
    float4 acc = make_float4(0.f, 0.f, 0.f, 0.f);

    for (int t = wi; t < T; t += WBATCH) {
        if (mb[t] == 0) break;                   // left-packed mask: done
        const float4 hv = *(const float4*)(hb + (size_t)t * U + (lane << 2));
        float p = st.x * hv.x + st.y * hv.y + st.z * hv.z + st.w * hv.w;
#pragma unroll
        for (int off = 32; off; off >>= 1) p += __shfl_xor(p, off, 64);
        if (lane == 0) scb[t] = p;               // stash raw score for pass2
        const float nm = fmaxf(m, p);
        const float s0 = __expf(m - nm);         // exp(-inf)=0 on first iter
        const float e  = __expf(p - nm);
        l = l * s0 + e;
        acc.x = fmaf(acc.x, s0, e * hv.x);
        acc.y = fmaf(acc.y, s0, e * hv.y);
        acc.z = fmaf(acc.z, s0, e * hv.z);
        acc.w = fmaf(acc.w, s0, e * hv.w);
        m = nm;
    }

    // block-level reduce of 4 waves' (m, l, acc) -> one partial per block
    __shared__ float sm[WPB], sl[WPB];
    __shared__ float sacc[WPB * U];
    *(float4*)&sacc[wave * U + (lane << 2)] = acc;
    if (lane == 0) { sm[wave] = m; sl[wave] = l; }
    __syncthreads();

    const float M = fmaxf(fmaxf(sm[0], sm[1]), fmaxf(sm[2], sm[3]));
    float Lb = 0.f, a = 0.f;
#pragma unroll
    for (int w = 0; w < WPB; ++w) {
        const float sc = __expf(sm[w] - M);
        Lb += sl[w] * sc;
        a  += sacc[w * U + tid] * sc;
    }
    const int pidx = b * SB + sblk;
    if (tid == 0) { pm[pidx] = M; pl[pidx] = Lb; }
    pacc[(size_t)pidx * U + tid] = a;
}

// ---------------- kernel 2: combine partials, finalize ct and alpha -----------
__global__ __launch_bounds__(256) void pass2(
    const int* __restrict__ mask, const float* __restrict__ pm,
    const float* __restrict__ pl, const float* __restrict__ pacc,
    float* __restrict__ ct, float* __restrict__ alpha)
{
    const int b = blockIdx.x, tid = threadIdx.x;
    float M = -INFINITY;
#pragma unroll
    for (int s = 0; s < SB; ++s) M = fmaxf(M, pm[b * SB + s]);
    float L = 0.f, a = 0.f;
#pragma unroll
    for (int s = 0; s < SB; ++s) {
        const float sc = __expf(pm[b * SB + s] - M);
        L += pl[b * SB + s] * sc;
        a += pacc[(size_t)(b * SB + s) * U + tid] * sc;
    }
    const float invL = 1.f / L;
    ct[b * U + tid] = a * invL;

    const int* mb = mask + b * T;
    float*     ab = alpha + (size_t)b * T;
    for (int t = tid; t < T; t += 256)
        ab[t] = mb[t] ? __expf(ab[t] - M) * invL : 0.f;
}

extern "C" void kernel_launch(void* const* d_in, const int* in_sizes, int n_in,
                              void* d_out, int out_size, void* d_ws, size_t ws_size,
                              hipStream_t stream) {
    const float* h    = (const float*)d_in[0];   // [B,T,U]
    const float* ds   = (const float*)d_in[1];   // [B,D_DEC]
    const int*   mask = (const int*)d_in[2];     // [B,T]
    const float* W    = (const float*)d_in[3];   // [D_DEC,U]
    const float* bias = (const float*)d_in[4];   // [U]

    float* out   = (float*)d_out;
    float* ct    = out;                          // [B,U]
    float* alpha = out + B * U;                  // [B,T] (also score scratch)

    float* ws    = (float*)d_ws;
    float* state = ws;                           // B*U
    float* pm    = state + B * U;                // B*SB
    float* pl    = pm + B * SB;                  // B*SB
    float* pacc  = pl + B * SB;                  // B*SB*U

    state_kernel<<<B, 256, 0, stream>>>(ds, W, bias, state);
    pass1<<<B * SB, 256, 0, stream>>>(h, mask, state, alpha, pm, pl, pacc);
    pass2<<<B, 256, 0, stream>>>(mask, pm, pl, pacc, ct, alpha);
}

// Round 2
// 364.651 us; speedup vs baseline: 1.0239x; 1.0239x over previous
//
#include <hip/hip_runtime.h>

#define B 64
#define T 4096
#define U 256
#define SB 32            // pass1 blocks per batch
#define WPB 4            // waves per block
#define WBATCH (SB*WPB)  // 128 waves per batch

// ---------------- kernel 0: state[b,u] = decoder_s[b,:] @ Wa_w[:,u] + b[u] ----
__global__ __launch_bounds__(256) void state_kernel(
    const float* __restrict__ ds, const float* __restrict__ W,
    const float* __restrict__ bias, float* __restrict__ state)
{
    const int b = blockIdx.x, u = threadIdx.x;
    __shared__ float ss[U];
    ss[u] = ds[b * U + u];
    __syncthreads();
    float acc = bias[u];
#pragma unroll 8
    for (int d = 0; d < U; ++d) acc = fmaf(ss[d], W[d * U + u], acc);
    state[b * U + u] = acc;
}

// ---------------- kernel 1: fused score + online softmax + context partials ---
// Each wave handles strided t; lanes cover u (4 floats/lane). encoder_h read ONCE.
// Length of the left-packed mask found via 2-step ballot search (no in-loop
// mask loads -> loop is countable -> h loads pipeline ahead of the softmax).
__global__ __launch_bounds__(256) void pass1(
    const float* __restrict__ h, const int* __restrict__ mask,
    const float* __restrict__ state, float* __restrict__ score,
    float* __restrict__ pm, float* __restrict__ pl, float* __restrict__ pacc)
{
    const int b    = blockIdx.x / SB;
    const int sblk = blockIdx.x % SB;
    const int tid  = threadIdx.x;
    const int wave = tid >> 6, lane = tid & 63;
    const int wi   = sblk * WPB + wave;          // wave index within batch, 0..127

    const int* mb = mask + b * T;
    // --- left-packed length via 2 ballots: sample stride 64, then fine scan ---
    const int s1 = mb[lane << 6];                           // t = 64*lane
    const int k1 = __popcll(__ballot(s1 != 0));             // >=1 (len >= 1024)
    const int base = (k1 - 1) << 6;
    const int s2 = mb[base + lane];
    const int len = base + __popcll(__ballot(s2 != 0));     // exact length

    const float4 st = *(const float4*)(state + b * U + (lane << 2));
    const float* hb = h + (size_t)b * T * U;
    float*      scb = score + (size_t)b * T;

    float  m = -INFINITY, l = 0.f;
    float4 acc = make_float4(0.f, 0.f, 0.f, 0.f);

    int t = wi;
    float4 hv = make_float4(0.f, 0.f, 0.f, 0.f);
    if (t < len) hv = *(const float4*)(hb + (size_t)t * U + (lane << 2));

    while (t < len) {
        const int tn = t + WBATCH;
        const int tc = (tn < len) ? tn : t;      // clamped prefetch address
        const float4 hn = *(const float4*)(hb + (size_t)tc * U + (lane << 2));

        float p = st.x * hv.x + st.y * hv.y + st.z * hv.z + st.w * hv.w;
#pragma unroll
        for (int off = 32; off; off >>= 1) p += __shfl_xor(p, off, 64);
        if (lane == 0) scb[t] = p;               // stash raw score for pass2

        if (p > m) {                             // wave-uniform branch
            const float s0 = __expf(m - p);      // exp(-inf)=0 on first iter
            l = fmaf(l, s0, 1.0f);
            acc.x = fmaf(acc.x, s0, hv.x);
            acc.y = fmaf(acc.y, s0, hv.y);
            acc.z = fmaf(acc.z, s0, hv.z);
            acc.w = fmaf(acc.w, s0, hv.w);
            m = p;
        } else {
            const float e = __expf(p - m);
            l += e;
            acc.x = fmaf(e, hv.x, acc.x);
            acc.y = fmaf(e, hv.y, acc.y);
            acc.z = fmaf(e, hv.z, acc.z);
            acc.w = fmaf(e, hv.w, acc.w);
        }
        hv = hn;
        t  = tn;
    }

    // block-level reduce of 4 waves' (m, l, acc) -> one partial per block
    __shared__ float sm[WPB], sl[WPB];
    __shared__ float sacc[WPB * U];
    *(float4*)&sacc[wave * U + (lane << 2)] = acc;
    if (lane == 0) { sm[wave] = m; sl[wave] = l; }
    __syncthreads();

    const float M = fmaxf(fmaxf(sm[0], sm[1]), fmaxf(sm[2], sm[3]));
    float Lb = 0.f, a = 0.f;
#pragma unroll
    for (int w = 0; w < WPB; ++w) {
        const float sc = __expf(sm[w] - M);
        Lb += sl[w] * sc;
        a  += sacc[w * U + tid] * sc;
    }
    const int pidx = b * SB + sblk;
    if (tid == 0) { pm[pidx] = M; pl[pidx] = Lb; }
    pacc[(size_t)pidx * U + tid] = a;
}

// ---------------- kernel 2: combine partials, finalize ct and alpha -----------
__global__ __launch_bounds__(256) void pass2(
    const int* __restrict__ mask, const float* __restrict__ pm,
    const float* __restrict__ pl, const float* __restrict__ pacc,
    float* __restrict__ ct, float* __restrict__ alpha)
{
    const int b = blockIdx.x, tid = threadIdx.x;
    float M = -INFINITY;
#pragma unroll
    for (int s = 0; s < SB; ++s) M = fmaxf(M, pm[b * SB + s]);
    float L = 0.f, a = 0.f;
#pragma unroll
    for (int s = 0; s < SB; ++s) {
        const float sc = __expf(pm[b * SB + s] - M);
        L += pl[b * SB + s] * sc;
        a += pacc[(size_t)(b * SB + s) * U + tid] * sc;
    }
    const float invL = 1.f / L;
    ct[b * U + tid] = a * invL;

    const int4*   mb4 = (const int4*)(mask + b * T);
    float4*       ab4 = (float4*)(alpha + (size_t)b * T);
    for (int i = tid; i < T / 4; i += 256) {
        const int4   mv = mb4[i];
        float4       av = ab4[i];
        av.x = mv.x ? __expf(av.x - M) * invL : 0.f;
        av.y = mv.y ? __expf(av.y - M) * invL : 0.f;
        av.z = mv.z ? __expf(av.z - M) * invL : 0.f;
        av.w = mv.w ? __expf(av.w - M) * invL : 0.f;
        ab4[i] = av;
    }
}

extern "C" void kernel_launch(void* const* d_in, const int* in_sizes, int n_in,
                              void* d_out, int out_size, void* d_ws, size_t ws_size,
                              hipStream_t stream) {
    const float* h    = (const float*)d_in[0];   // [B,T,U]
    const float* ds   = (const float*)d_in[1];   // [B,D_DEC]
    const int*   mask = (const int*)d_in[2];     // [B,T]
    const float* W    = (const float*)d_in[3];   // [D_DEC,U]
    const float* bias = (const float*)d_in[4];   // [U]

    float* out   = (float*)d_out;
    float* ct    = out;                          // [B,U]
    float* alpha = out + B * U;                  // [B,T] (also score scratch)

    float* ws    = (float*)d_ws;
    float* state = ws;                           // B*U
    float* pm    = state + B * U;                // B*SB
    float* pl    = pm + B * SB;                  // B*SB
    float* pacc  = pl + B * SB;                  // B*SB*U

    state_kernel<<<B, 256, 0, stream>>>(ds, W, bias, state);
    pass1<<<B * SB, 256, 0, stream>>>(h, mask, state, alpha, pm, pl, pacc);
    pass2<<<B, 256, 0, stream>>>(mask, pm, pl, pacc, ct, alpha);
}

// Round 3
// 362.386 us; speedup vs baseline: 1.0303x; 1.0062x over previous
//
#include <hip/hip_runtime.h>

#define B 64
#define T 4096
#define U 256
#define SB 32            // pass1 blocks per batch
#define WPB 4            // waves per block
#define WBATCH (SB*WPB)  // 128 waves per batch

// ---------------- kernel 0: state[b,u] = decoder_s[b,:] @ Wa_w[:,u] + b[u] ----
__global__ __launch_bounds__(256) void state_kernel(
    const float* __restrict__ ds, const float* __restrict__ W,
    const float* __restrict__ bias, float* __restrict__ state)
{
    const int b = blockIdx.x, u = threadIdx.x;
    __shared__ float ss[U];
    ss[u] = ds[b * U + u];
    __syncthreads();
    float acc = bias[u];
#pragma unroll 8
    for (int d = 0; d < U; ++d) acc = fmaf(ss[d], W[d * U + u], acc);
    state[b * U + u] = acc;
}

__device__ __forceinline__ int packed_len(const int* __restrict__ mb, int lane) {
    // left-packed mask length via 2 ballots (len >= 64 assumed; here len >= 1024)
    const int s1 = mb[lane << 6];                           // sample stride 64
    const int k1 = __popcll(__ballot(s1 != 0));
    const int base = (k1 - 1) << 6;
    const int s2 = mb[base + lane];
    return base + __popcll(__ballot(s2 != 0));
}

// ---------------- kernel 1: fused score + online softmax + context partials ---
// b = blockIdx % B so consecutive blocks (-> same CU/XCD) mix batch lengths:
// balances the tail when short batches retire early.
__global__ __launch_bounds__(256) void pass1(
    const float* __restrict__ h, const int* __restrict__ mask,
    const float* __restrict__ state, float* __restrict__ score,
    float* __restrict__ pm, float* __restrict__ pl, float* __restrict__ pacc)
{
    const int b    = blockIdx.x & (B - 1);
    const int sblk = blockIdx.x >> 6;
    const int tid  = threadIdx.x;
    const int wave = tid >> 6, lane = tid & 63;
    const int wi   = sblk * WPB + wave;          // wave index within batch, 0..127

    const int len = packed_len(mask + b * T, lane);

    const float4 st = *(const float4*)(state + b * U + (lane << 2));
    const float* hb = h + (size_t)b * T * U;
    float*      scb = score + (size_t)b * T;

    float  m = -INFINITY, l = 0.f;
    float4 acc = make_float4(0.f, 0.f, 0.f, 0.f);

    int t = wi;
    float4 hv = make_float4(0.f, 0.f, 0.f, 0.f);
    if (t < len) hv = *(const float4*)(hb + (size_t)t * U + (lane << 2));

    while (t < len) {
        const int tn = t + WBATCH;
        const int tc = (tn < len) ? tn : t;      // clamped prefetch address
        const float4 hn = *(const float4*)(hb + (size_t)tc * U + (lane << 2));

        float p = st.x * hv.x + st.y * hv.y + st.z * hv.z + st.w * hv.w;
#pragma unroll
        for (int off = 32; off; off >>= 1) p += __shfl_xor(p, off, 64);
        if (lane == 0) scb[t] = p;               // stash raw score for pass2

        if (p > m) {                             // wave-uniform branch
            const float s0 = __expf(m - p);      // exp(-inf)=0 on first iter
            l = fmaf(l, s0, 1.0f);
            acc.x = fmaf(acc.x, s0, hv.x);
            acc.y = fmaf(acc.y, s0, hv.y);
            acc.z = fmaf(acc.z, s0, hv.z);
            acc.w = fmaf(acc.w, s0, hv.w);
            m = p;
        } else {
            const float e = __expf(p - m);
            l += e;
            acc.x = fmaf(e, hv.x, acc.x);
            acc.y = fmaf(e, hv.y, acc.y);
            acc.z = fmaf(e, hv.z, acc.z);
            acc.w = fmaf(e, hv.w, acc.w);
        }
        hv = hn;
        t  = tn;
    }

    // block-level reduce of 4 waves' (m, l, acc) -> one partial per block
    __shared__ float sm[WPB], sl[WPB];
    __shared__ float sacc[WPB * U];
    *(float4*)&sacc[wave * U + (lane << 2)] = acc;
    if (lane == 0) { sm[wave] = m; sl[wave] = l; }
    __syncthreads();

    const float M = fmaxf(fmaxf(sm[0], sm[1]), fmaxf(sm[2], sm[3]));
    float Lb = 0.f, a = 0.f;
#pragma unroll
    for (int w = 0; w < WPB; ++w) {
        const float sc = __expf(sm[w] - M);
        Lb += sl[w] * sc;
        a  += sacc[w * U + tid] * sc;
    }
    const int pidx = b * SB + sblk;
    if (tid == 0) { pm[pidx] = M; pl[pidx] = Lb; }
    pacc[(size_t)pidx * U + tid] = a;
}

// ---------------- kernel 2: combine partials, finalize ct and alpha -----------
__global__ __launch_bounds__(256) void pass2(
    const int* __restrict__ mask, const float* __restrict__ pm,
    const float* __restrict__ pl, const float* __restrict__ pacc,
    float* __restrict__ ct, float* __restrict__ alpha)
{
    const int b = blockIdx.x, tid = threadIdx.x;
    const int lane = tid & 63;
    const int len = packed_len(mask + b * T, lane);   // same result in all waves

    float M = -INFINITY;
#pragma unroll
    for (int s = 0; s < SB; ++s) M = fmaxf(M, pm[b * SB + s]);
    float L = 0.f, a = 0.f;
#pragma unroll
    for (int s = 0; s < SB; ++s) {
        const float sc = __expf(pm[b * SB + s] - M);
        L += pl[b * SB + s] * sc;
        a += pacc[(size_t)(b * SB + s) * U + tid] * sc;
    }
    const float invL = 1.f / L;
    ct[b * U + tid] = a * invL;

    float*  ap  = alpha + (size_t)b * T;
    float4* ab4 = (float4*)ap;
    for (int i = tid; i < T / 4; i += 256) {
        const int t0 = i << 2;
        float4 av;
        if (t0 + 4 <= len) {                     // fully valid chunk
            av = ab4[i];
            av.x = __expf(av.x - M) * invL;
            av.y = __expf(av.y - M) * invL;
            av.z = __expf(av.z - M) * invL;
            av.w = __expf(av.w - M) * invL;
        } else if (t0 >= len) {                  // fully padded: write zeros
            av = make_float4(0.f, 0.f, 0.f, 0.f);
        } else {                                 // boundary chunk
            av.x = (t0 + 0 < len) ? __expf(ap[t0 + 0] - M) * invL : 0.f;
            av.y = (t0 + 1 < len) ? __expf(ap[t0 + 1] - M) * invL : 0.f;
            av.z = (t0 + 2 < len) ? __expf(ap[t0 + 2] - M) * invL : 0.f;
            av.w = (t0 + 3 < len) ? __expf(ap[t0 + 3] - M) * invL : 0.f;
        }
        ab4[i] = av;
    }
}

extern "C" void kernel_launch(void* const* d_in, const int* in_sizes, int n_in,
                              void* d_out, int out_size, void* d_ws, size_t ws_size,
                              hipStream_t stream) {
    const float* h    = (const float*)d_in[0];   // [B,T,U]
    const float* ds   = (const float*)d_in[1];   // [B,D_DEC]
    const int*   mask = (const int*)d_in[2];     // [B,T]
    const float* W    = (const float*)d_in[3];   // [D_DEC,U]
    const float* bias = (const float*)d_in[4];   // [U]

    float* out   = (float*)d_out;
    float* ct    = out;                          // [B,U]
    float* alpha = out + B * U;                  // [B,T] (also score scratch)

    float* ws    = (float*)d_ws;
    float* state = ws;                           // B*U
    float* pm    = state + B * U;                // B*SB
    float* pl    = pm + B * SB;                  // B*SB
    float* pacc  = pl + B * SB;                  // B*SB*U

    state_kernel<<<B, 256, 0, stream>>>(ds, W, bias, state);
    pass1<<<B * SB, 256, 0, stream>>>(h, mask, state, alpha, pm, pl, pacc);
    pass2<<<B, 256, 0, stream>>>(mask, pm, pl, pacc, ct, alpha);
}